// Round 1
// baseline (169.501 us; speedup 1.0000x reference)
//
#include <hip/hip_runtime.h>
#include <hip/hip_bf16.h>

typedef __attribute__((ext_vector_type(8))) short bfx8;
typedef __attribute__((ext_vector_type(4))) float fx4;

static __device__ __forceinline__ short f2bf(float f) {
  union { float f; unsigned u; } v; v.f = f;
  unsigned r = v.u + 0x7fffu + ((v.u >> 16) & 1u);
  return (short)(r >> 16);
}

constexpr int Bz = 8, Sq = 512, Em = 1024, Hn = 16, Dh = 64;
constexpr int Mrows = Bz * Sq;  // 4096

// ---------------- GEMM config ----------------
constexpr int BM = 128, BN = 128, BK = 32, LDT = 56;  // LDT: +24 pad -> 2-way LDS conflicts, 16B aligned rows

// q/k/v projection: C = X @ W^T + bias + pe, output bf16 scattered to [B,H,S,Dh]
__global__ __launch_bounds__(256) void gemm_qkv_kernel(
    const float* __restrict__ q_in, const float* __restrict__ k_in,
    const float* __restrict__ v_in,
    const float* __restrict__ Wq, const float* __restrict__ Wk,
    const float* __restrict__ Wv,
    const float* __restrict__ bq, const float* __restrict__ bk,
    const float* __restrict__ bv,
    const float* __restrict__ pos,
    short* __restrict__ qb, short* __restrict__ kb, short* __restrict__ vb)
{
  __shared__ short As[BM * LDT];
  __shared__ short Bs[BN * LDT];
  const int z = blockIdx.z;
  const float* A = (z == 0) ? q_in : (z == 1) ? k_in : v_in;
  const float* W = (z == 0) ? Wq : (z == 1) ? Wk : Wv;
  const float* bias = (z == 0) ? bq : (z == 1) ? bk : bv;
  short* dst = (z == 0) ? qb : (z == 1) ? kb : vb;

  const int m0 = blockIdx.x * BM, n0 = blockIdx.y * BN;
  const int t = threadIdx.x, lane = t & 63, wave = t >> 6;
  const int wr = wave >> 1, wc = wave & 1;
  const int fr = lane & 15, fq = lane >> 4;
  const int srow = t >> 1, scol = (t & 1) * 16;

  fx4 acc[4][4] = {};

  for (int k0 = 0; k0 < Em; k0 += BK) {
    // stage A (f32 -> bf16)
    const float* pa = A + (size_t)(m0 + srow) * Em + k0 + scol;
    fx4 a0 = *(const fx4*)pa;
    fx4 a1 = *(const fx4*)(pa + 4);
    fx4 a2 = *(const fx4*)(pa + 8);
    fx4 a3 = *(const fx4*)(pa + 12);
    const float* pb = W + (size_t)(n0 + srow) * Em + k0 + scol;
    fx4 b0 = *(const fx4*)pb;
    fx4 b1 = *(const fx4*)(pb + 4);
    fx4 b2 = *(const fx4*)(pb + 8);
    fx4 b3 = *(const fx4*)(pb + 12);
    bfx8 wa0 = { f2bf(a0[0]), f2bf(a0[1]), f2bf(a0[2]), f2bf(a0[3]),
                 f2bf(a1[0]), f2bf(a1[1]), f2bf(a1[2]), f2bf(a1[3]) };
    bfx8 wa1 = { f2bf(a2[0]), f2bf(a2[1]), f2bf(a2[2]), f2bf(a2[3]),
                 f2bf(a3[0]), f2bf(a3[1]), f2bf(a3[2]), f2bf(a3[3]) };
    bfx8 wb0 = { f2bf(b0[0]), f2bf(b0[1]), f2bf(b0[2]), f2bf(b0[3]),
                 f2bf(b1[0]), f2bf(b1[1]), f2bf(b1[2]), f2bf(b1[3]) };
    bfx8 wb1 = { f2bf(b2[0]), f2bf(b2[1]), f2bf(b2[2]), f2bf(b2[3]),
                 f2bf(b3[0]), f2bf(b3[1]), f2bf(b3[2]), f2bf(b3[3]) };
    *(bfx8*)&As[srow * LDT + scol] = wa0;
    *(bfx8*)&As[srow * LDT + scol + 8] = wa1;
    *(bfx8*)&Bs[srow * LDT + scol] = wb0;
    *(bfx8*)&Bs[srow * LDT + scol + 8] = wb1;
    __syncthreads();

    bfx8 af[4], bfr[4];
#pragma unroll
    for (int m = 0; m < 4; ++m)
      af[m] = *(const bfx8*)&As[(wr * 64 + m * 16 + fr) * LDT + fq * 8];
#pragma unroll
    for (int n = 0; n < 4; ++n)
      bfr[n] = *(const bfx8*)&Bs[(wc * 64 + n * 16 + fr) * LDT + fq * 8];
#pragma unroll
    for (int m = 0; m < 4; ++m)
#pragma unroll
      for (int n = 0; n < 4; ++n)
        acc[m][n] = __builtin_amdgcn_mfma_f32_16x16x32_bf16(af[m], bfr[n], acc[m][n], 0, 0, 0);
    __syncthreads();
  }

  // epilogue: + bias + pe, scatter bf16 into [B,H,S,Dh]
#pragma unroll
  for (int m = 0; m < 4; ++m) {
    const int mm = m0 + wr * 64 + m * 16 + fq * 4;
#pragma unroll
    for (int n = 0; n < 4; ++n) {
      const int nn = n0 + wc * 64 + n * 16 + fr;
      const float bb = bias[nn];
      const int h = nn >> 6, d = nn & 63;
#pragma unroll
      for (int i = 0; i < 4; ++i) {
        const int row = mm + i;
        const int s = row & (Sq - 1), b = row >> 9;
        const float val = acc[m][n][i] + bb + pos[(size_t)s * Em + nn];
        dst[(((size_t)b * Hn + h) * Sq + s) * Dh + d] = f2bf(val);
      }
    }
  }
}

// output projection: out = wv @ Wo^T + bo (A is bf16 in ws, out f32)
__global__ __launch_bounds__(256) void gemm_out_kernel(
    const short* __restrict__ wv, const float* __restrict__ Wo,
    const float* __restrict__ bo, float* __restrict__ out)
{
  __shared__ short As[BM * LDT];
  __shared__ short Bs[BN * LDT];

  const int m0 = blockIdx.x * BM, n0 = blockIdx.y * BN;
  const int t = threadIdx.x, lane = t & 63, wave = t >> 6;
  const int wr = wave >> 1, wc = wave & 1;
  const int fr = lane & 15, fq = lane >> 4;
  const int srow = t >> 1, scol = (t & 1) * 16;

  fx4 acc[4][4] = {};

  for (int k0 = 0; k0 < Em; k0 += BK) {
    const short* pa = wv + (size_t)(m0 + srow) * Em + k0 + scol;
    bfx8 wa0 = *(const bfx8*)pa;
    bfx8 wa1 = *(const bfx8*)(pa + 8);
    const float* pb = Wo + (size_t)(n0 + srow) * Em + k0 + scol;
    fx4 b0 = *(const fx4*)pb;
    fx4 b1 = *(const fx4*)(pb + 4);
    fx4 b2 = *(const fx4*)(pb + 8);
    fx4 b3 = *(const fx4*)(pb + 12);
    bfx8 wb0 = { f2bf(b0[0]), f2bf(b0[1]), f2bf(b0[2]), f2bf(b0[3]),
                 f2bf(b1[0]), f2bf(b1[1]), f2bf(b1[2]), f2bf(b1[3]) };
    bfx8 wb1 = { f2bf(b2[0]), f2bf(b2[1]), f2bf(b2[2]), f2bf(b2[3]),
                 f2bf(b3[0]), f2bf(b3[1]), f2bf(b3[2]), f2bf(b3[3]) };
    *(bfx8*)&As[srow * LDT + scol] = wa0;
    *(bfx8*)&As[srow * LDT + scol + 8] = wa1;
    *(bfx8*)&Bs[srow * LDT + scol] = wb0;
    *(bfx8*)&Bs[srow * LDT + scol + 8] = wb1;
    __syncthreads();

    bfx8 af[4], bfr[4];
#pragma unroll
    for (int m = 0; m < 4; ++m)
      af[m] = *(const bfx8*)&As[(wr * 64 + m * 16 + fr) * LDT + fq * 8];
#pragma unroll
    for (int n = 0; n < 4; ++n)
      bfr[n] = *(const bfx8*)&Bs[(wc * 64 + n * 16 + fr) * LDT + fq * 8];
#pragma unroll
    for (int m = 0; m < 4; ++m)
#pragma unroll
      for (int n = 0; n < 4; ++n)
        acc[m][n] = __builtin_amdgcn_mfma_f32_16x16x32_bf16(af[m], bfr[n], acc[m][n], 0, 0, 0);
    __syncthreads();
  }

#pragma unroll
  for (int m = 0; m < 4; ++m) {
    const int mm = m0 + wr * 64 + m * 16 + fq * 4;
#pragma unroll
    for (int n = 0; n < 4; ++n) {
      const int nn = n0 + wc * 64 + n * 16 + fr;
      const float bb = bo[nn];
#pragma unroll
      for (int i = 0; i < 4; ++i) {
        out[(size_t)(mm + i) * Em + nn] = acc[m][n][i] + bb;
      }
    }
  }
}

// ---------------- Attention ----------------
constexpr int KVB = 64, LDK = 72;  // LDK: stride 144B -> 2-way conflicts, 16B aligned

__global__ __launch_bounds__(256) void attn_kernel(
    const short* __restrict__ qb, const short* __restrict__ kb,
    const short* __restrict__ vb, short* __restrict__ wv)
{
  __shared__ short Ks[KVB * LDK];        // K tile [kv][d]
  __shared__ short Vt[Dh * LDK];         // V tile transposed [d][kv]
  __shared__ short Ps[4][16 * LDK];      // per-wave P [q][kv]

  const int bh = blockIdx.x;   // b*16 + h
  const int qt = blockIdx.y;   // q tile of 64
  const int t = threadIdx.x, lane = t & 63, wave = t >> 6;
  const int fr = lane & 15, fq = lane >> 4;

  const size_t base = (size_t)bh * Sq * Dh;
  const int q0 = qt * 64 + wave * 16;

  // Q fragments held in registers for the whole kernel
  bfx8 qf[2];
  {
    const short* qp = qb + base + (size_t)(q0 + fr) * Dh;
    qf[0] = *(const bfx8*)(qp + fq * 8);
    qf[1] = *(const bfx8*)(qp + 32 + fq * 8);
  }

  float mrow[4] = { -1e30f, -1e30f, -1e30f, -1e30f };
  float lrow[4] = { 0.f, 0.f, 0.f, 0.f };
  fx4 oacc[4] = {};

  const int kr = t >> 2, kc = (t & 3) * 16;   // K staging: 16 elems/thread
  const int vr = t & 63, vdb = (t >> 6) * 16; // V staging (transposed scatter)

  for (int kv0 = 0; kv0 < Sq; kv0 += KVB) {
    {  // stage K [64][64]
      const short* kp = kb + base + (size_t)(kv0 + kr) * Dh + kc;
      bfx8 u0 = *(const bfx8*)kp;
      bfx8 u1 = *(const bfx8*)(kp + 8);
      *(bfx8*)&Ks[kr * LDK + kc] = u0;
      *(bfx8*)&Ks[kr * LDK + kc + 8] = u1;
    }
    {  // stage V transposed -> Vt[d][kv]
      const short* vp = vb + base + (size_t)(kv0 + vr) * Dh + vdb;
      bfx8 u0 = *(const bfx8*)vp;
      bfx8 u1 = *(const bfx8*)(vp + 8);
#pragma unroll
      for (int j = 0; j < 8; ++j) {
        Vt[(vdb + j) * LDK + vr] = u0[j];
        Vt[(vdb + 8 + j) * LDK + vr] = u1[j];
      }
    }
    __syncthreads();

    // S = Q K^T (raw, scale applied in softmax)
    fx4 sa[4] = {};
#pragma unroll
    for (int nf = 0; nf < 4; ++nf) {
#pragma unroll
      for (int ks = 0; ks < 2; ++ks) {
        bfx8 kf = *(const bfx8*)&Ks[(nf * 16 + fr) * LDK + ks * 32 + fq * 8];
        sa[nf] = __builtin_amdgcn_mfma_f32_16x16x32_bf16(qf[ks], kf, sa[nf], 0, 0, 0);
      }
    }

    // online softmax; rows of this wave: q = q0 + fq*4 + i
#pragma unroll
    for (int i = 0; i < 4; ++i) {
      float mx = fmaxf(fmaxf(sa[0][i], sa[1][i]), fmaxf(sa[2][i], sa[3][i]));
      mx = fmaxf(mx, __shfl_xor(mx, 1));
      mx = fmaxf(mx, __shfl_xor(mx, 2));
      mx = fmaxf(mx, __shfl_xor(mx, 4));
      mx = fmaxf(mx, __shfl_xor(mx, 8));
      mx *= 0.125f;  // 1/sqrt(64)
      const float mn = fmaxf(mrow[i], mx);
      const float alpha = __expf(mrow[i] - mn);
      mrow[i] = mn;
      float rs = 0.f;
#pragma unroll
      for (int nf = 0; nf < 4; ++nf) {
        const float p = __expf(sa[nf][i] * 0.125f - mn);
        rs += p;
        Ps[wave][(fq * 4 + i) * LDK + nf * 16 + fr] = f2bf(p);
      }
      rs += __shfl_xor(rs, 1);
      rs += __shfl_xor(rs, 2);
      rs += __shfl_xor(rs, 4);
      rs += __shfl_xor(rs, 8);
      lrow[i] = lrow[i] * alpha + rs;
#pragma unroll
      for (int df = 0; df < 4; ++df) oacc[df][i] *= alpha;
    }
    __syncthreads();  // P visible; K reads done

    // O += P @ V
    bfx8 pf[2];
    pf[0] = *(const bfx8*)&Ps[wave][fr * LDK + fq * 8];
    pf[1] = *(const bfx8*)&Ps[wave][fr * LDK + 32 + fq * 8];
#pragma unroll
    for (int df = 0; df < 4; ++df) {
#pragma unroll
      for (int ks = 0; ks < 2; ++ks) {
        bfx8 vf = *(const bfx8*)&Vt[(df * 16 + fr) * LDK + ks * 32 + fq * 8];
        oacc[df] = __builtin_amdgcn_mfma_f32_16x16x32_bf16(pf[ks], vf, oacc[df], 0, 0, 0);
      }
    }
    __syncthreads();  // protect Ks/Vt before next staging
  }

  // write wv [B,S,E] bf16
  const int b = bh >> 4, h = bh & 15;
#pragma unroll
  for (int df = 0; df < 4; ++df) {
    const int d = df * 16 + fr;
#pragma unroll
    for (int i = 0; i < 4; ++i) {
      const int qrow = q0 + fq * 4 + i;
      const float o = oacc[df][i] / lrow[i];
      wv[((size_t)b * Sq + qrow) * Em + h * Dh + d] = f2bf(o);
    }
  }
}

extern "C" void kernel_launch(void* const* d_in, const int* in_sizes, int n_in,
                              void* d_out, int out_size, void* d_ws, size_t ws_size,
                              hipStream_t stream) {
  (void)in_sizes; (void)n_in; (void)out_size; (void)ws_size;
  const float* query = (const float*)d_in[0];
  const float* key   = (const float*)d_in[1];
  const float* value = (const float*)d_in[2];
  const float* Wq = (const float*)d_in[3];
  const float* bq = (const float*)d_in[4];
  const float* Wk = (const float*)d_in[5];
  const float* bk = (const float*)d_in[6];
  const float* Wv = (const float*)d_in[7];
  const float* bv = (const float*)d_in[8];
  const float* Wo = (const float*)d_in[9];
  const float* bo = (const float*)d_in[10];
  const float* pos = (const float*)d_in[11];

  const size_t NE = (size_t)Bz * Sq * Em;  // 4,194,304 elements
  short* qb = (short*)d_ws;      // [B,H,S,Dh] bf16
  short* kb = qb + NE;
  short* vb = kb + NE;
  short* wv = vb + NE;           // [B,S,E] bf16

  gemm_qkv_kernel<<<dim3(Mrows / BM, Em / BN, 3), 256, 0, stream>>>(
      query, key, value, Wq, Wk, Wv, bq, bk, bv, pos, qb, kb, vb);
  attn_kernel<<<dim3(Bz * Hn, Sq / 64), 256, 0, stream>>>(qb, kb, vb, wv);
  gemm_out_kernel<<<dim3(Mrows / BM, Em / BN), 256, 0, stream>>>(
      wv, Wo, bo, (float*)d_out);
}

// Round 2
// 125.608 us; speedup vs baseline: 1.3494x; 1.3494x over previous
//
#include <hip/hip_runtime.h>
#include <hip/hip_bf16.h>

typedef __attribute__((ext_vector_type(8))) short bfx8;
typedef __attribute__((ext_vector_type(4))) float fx4;

static __device__ __forceinline__ short f2bf(float f) {
  union { float f; unsigned u; } v; v.f = f;
  unsigned r = v.u + 0x7fffu + ((v.u >> 16) & 1u);
  return (short)(r >> 16);
}

static __device__ __forceinline__ void gld16(const void* g, void* l) {
  // async global->LDS, 16B per lane; LDS dest = wave-uniform base + lane*16
  __builtin_amdgcn_global_load_lds(
      (const __attribute__((address_space(1))) void*)g,
      (__attribute__((address_space(3))) void*)l, 16, 0, 0);
}

constexpr int Bz = 8, Sq = 512, Em = 1024, Hn = 16, Dh = 64;
constexpr int Mrows = Bz * Sq;          // 4096
constexpr size_t NE = (size_t)Mrows * Em;  // 4,194,304
constexpr size_t WE = (size_t)Em * Em;     // 1,048,576

// ---------------- f32 -> bf16 pre-convert (memory-bound) ----------------
__global__ __launch_bounds__(256) void convert_kernel(
    const float* __restrict__ q, const float* __restrict__ k,
    const float* __restrict__ v,
    const float* __restrict__ Wq, const float* __restrict__ Wk,
    const float* __restrict__ Wv, const float* __restrict__ Wo,
    short* __restrict__ qx, short* __restrict__ kx, short* __restrict__ vx,
    short* __restrict__ wqb, short* __restrict__ wkb,
    short* __restrict__ wvb, short* __restrict__ wob)
{
  const int seg = blockIdx.y;
  const float* src; short* dst; size_t n;
  switch (seg) {
    case 0: src = q;  dst = qx;  n = NE; break;
    case 1: src = k;  dst = kx;  n = NE; break;
    case 2: src = v;  dst = vx;  n = NE; break;
    case 3: src = Wq; dst = wqb; n = WE; break;
    case 4: src = Wk; dst = wkb; n = WE; break;
    case 5: src = Wv; dst = wvb; n = WE; break;
    default: src = Wo; dst = wob; n = WE; break;
  }
  const size_t i = ((size_t)blockIdx.x * 256 + threadIdx.x) * 8;
  if (i >= n) return;
  fx4 a = *(const fx4*)(src + i);
  fx4 b = *(const fx4*)(src + i + 4);
  bfx8 o = { f2bf(a[0]), f2bf(a[1]), f2bf(a[2]), f2bf(a[3]),
             f2bf(b[0]), f2bf(b[1]), f2bf(b[2]), f2bf(b[3]) };
  *(bfx8*)(dst + i) = o;
}

// ---------------- m97-structure bf16 GEMM ----------------
// 128x128 tile, BK=32, 4 waves (2x2), 4x4 16x16x32 frags/wave,
// global_load_lds(16B) into linear LDS [128][32] bf16.

// QKV projection: C = X @ W^T + bias + pe, bf16 scatter to [B,H,S,Dh]
__global__ __launch_bounds__(256) void gemm_qkv_bf16(
    const short* __restrict__ qx, const short* __restrict__ kx,
    const short* __restrict__ vx,
    const short* __restrict__ Wqb, const short* __restrict__ Wkb,
    const short* __restrict__ Wvb,
    const float* __restrict__ bq, const float* __restrict__ bk,
    const float* __restrict__ bv,
    const float* __restrict__ pos,
    short* __restrict__ qb, short* __restrict__ kb, short* __restrict__ vb)
{
  __shared__ short As[128 * 32];
  __shared__ short Bs[128 * 32];
  const int z = blockIdx.z;
  const short* A = (z == 0) ? qx : (z == 1) ? kx : vx;
  const short* W = (z == 0) ? Wqb : (z == 1) ? Wkb : Wvb;
  const float* bias = (z == 0) ? bq : (z == 1) ? bk : bv;
  short* dst = (z == 0) ? qb : (z == 1) ? kb : vb;

  const int m0 = blockIdx.x * 128, n0 = blockIdx.y * 128;
  const int t = threadIdx.x, lane = t & 63, wave = t >> 6;
  const int wr = wave >> 1, wc = wave & 1;
  const int fr = lane & 15, fq = lane >> 4;

  // staging: chunk c (16B) -> row c>>2, col8 (c&3)*8 ; LDS byte off = c*16
  const int r0 = t >> 2, o0 = (t & 3) * 8;          // chunks [0,256)
  const int r1 = r0 + 64;                           // chunks [256,512)
  short* lA0 = As + wave * 512;                     // wave-uniform LDS bases
  short* lA1 = As + 2048 + wave * 512;
  short* lB0 = Bs + wave * 512;
  short* lB1 = Bs + 2048 + wave * 512;

  fx4 acc[4][4] = {};

  for (int k0 = 0; k0 < Em; k0 += 32) {
    gld16(A + (size_t)(m0 + r0) * Em + k0 + o0, lA0);
    gld16(A + (size_t)(m0 + r1) * Em + k0 + o0, lA1);
    gld16(W + (size_t)(n0 + r0) * Em + k0 + o0, lB0);
    gld16(W + (size_t)(n0 + r1) * Em + k0 + o0, lB1);
    __syncthreads();

    bfx8 af[4], bf[4];
#pragma unroll
    for (int m = 0; m < 4; ++m)
      af[m] = *(const bfx8*)&As[(wr * 64 + m * 16 + fr) * 32 + fq * 8];
#pragma unroll
    for (int n = 0; n < 4; ++n)
      bf[n] = *(const bfx8*)&Bs[(wc * 64 + n * 16 + fr) * 32 + fq * 8];
#pragma unroll
    for (int m = 0; m < 4; ++m)
#pragma unroll
      for (int n = 0; n < 4; ++n)
        acc[m][n] = __builtin_amdgcn_mfma_f32_16x16x32_bf16(af[m], bf[n], acc[m][n], 0, 0, 0);
    __syncthreads();
  }

  // epilogue: + bias + pe, scatter bf16 into [B,H,S,Dh]
#pragma unroll
  for (int m = 0; m < 4; ++m) {
    const int mm = m0 + wr * 64 + m * 16 + fq * 4;
#pragma unroll
    for (int n = 0; n < 4; ++n) {
      const int nn = n0 + wc * 64 + n * 16 + fr;
      const float bb = bias[nn];
      const int h = nn >> 6, d = nn & 63;
#pragma unroll
      for (int i = 0; i < 4; ++i) {
        const int row = mm + i;
        const int s = row & (Sq - 1), b = row >> 9;
        const float val = acc[m][n][i] + bb + pos[(size_t)s * Em + nn];
        dst[(((size_t)b * Hn + h) * Sq + s) * Dh + d] = f2bf(val);
      }
    }
  }
}

// output projection: out = wv @ Wo^T + bo  (f32 out)
__global__ __launch_bounds__(256) void gemm_out_bf16(
    const short* __restrict__ wv, const short* __restrict__ Wob,
    const float* __restrict__ bo, float* __restrict__ out)
{
  __shared__ short As[128 * 32];
  __shared__ short Bs[128 * 32];

  const int m0 = blockIdx.x * 128, n0 = blockIdx.y * 128;
  const int t = threadIdx.x, lane = t & 63, wave = t >> 6;
  const int wr = wave >> 1, wc = wave & 1;
  const int fr = lane & 15, fq = lane >> 4;

  const int r0 = t >> 2, o0 = (t & 3) * 8;
  const int r1 = r0 + 64;
  short* lA0 = As + wave * 512;
  short* lA1 = As + 2048 + wave * 512;
  short* lB0 = Bs + wave * 512;
  short* lB1 = Bs + 2048 + wave * 512;

  fx4 acc[4][4] = {};

  for (int k0 = 0; k0 < Em; k0 += 32) {
    gld16(wv + (size_t)(m0 + r0) * Em + k0 + o0, lA0);
    gld16(wv + (size_t)(m0 + r1) * Em + k0 + o0, lA1);
    gld16(Wob + (size_t)(n0 + r0) * Em + k0 + o0, lB0);
    gld16(Wob + (size_t)(n0 + r1) * Em + k0 + o0, lB1);
    __syncthreads();

    bfx8 af[4], bf[4];
#pragma unroll
    for (int m = 0; m < 4; ++m)
      af[m] = *(const bfx8*)&As[(wr * 64 + m * 16 + fr) * 32 + fq * 8];
#pragma unroll
    for (int n = 0; n < 4; ++n)
      bf[n] = *(const bfx8*)&Bs[(wc * 64 + n * 16 + fr) * 32 + fq * 8];
#pragma unroll
    for (int m = 0; m < 4; ++m)
#pragma unroll
      for (int n = 0; n < 4; ++n)
        acc[m][n] = __builtin_amdgcn_mfma_f32_16x16x32_bf16(af[m], bf[n], acc[m][n], 0, 0, 0);
    __syncthreads();
  }

#pragma unroll
  for (int m = 0; m < 4; ++m) {
    const int mm = m0 + wr * 64 + m * 16 + fq * 4;
#pragma unroll
    for (int n = 0; n < 4; ++n) {
      const int nn = n0 + wc * 64 + n * 16 + fr;
      const float bb = bo[nn];
#pragma unroll
      for (int i = 0; i < 4; ++i)
        out[(size_t)(mm + i) * Em + nn] = acc[m][n][i] + bb;
    }
  }
}

// ---------------- Attention (unchanged from R1) ----------------
constexpr int KVB = 64, LDK = 72;

__global__ __launch_bounds__(256) void attn_kernel(
    const short* __restrict__ qb, const short* __restrict__ kb,
    const short* __restrict__ vb, short* __restrict__ wv)
{
  __shared__ short Ks[KVB * LDK];
  __shared__ short Vt[Dh * LDK];
  __shared__ short Ps[4][16 * LDK];

  const int bh = blockIdx.x;
  const int qt = blockIdx.y;
  const int t = threadIdx.x, lane = t & 63, wave = t >> 6;
  const int fr = lane & 15, fq = lane >> 4;

  const size_t base = (size_t)bh * Sq * Dh;
  const int q0 = qt * 64 + wave * 16;

  bfx8 qf[2];
  {
    const short* qp = qb + base + (size_t)(q0 + fr) * Dh;
    qf[0] = *(const bfx8*)(qp + fq * 8);
    qf[1] = *(const bfx8*)(qp + 32 + fq * 8);
  }

  float mrow[4] = { -1e30f, -1e30f, -1e30f, -1e30f };
  float lrow[4] = { 0.f, 0.f, 0.f, 0.f };
  fx4 oacc[4] = {};

  const int kr = t >> 2, kc = (t & 3) * 16;
  const int vr = t & 63, vdb = (t >> 6) * 16;

  for (int kv0 = 0; kv0 < Sq; kv0 += KVB) {
    {
      const short* kp = kb + base + (size_t)(kv0 + kr) * Dh + kc;
      bfx8 u0 = *(const bfx8*)kp;
      bfx8 u1 = *(const bfx8*)(kp + 8);
      *(bfx8*)&Ks[kr * LDK + kc] = u0;
      *(bfx8*)&Ks[kr * LDK + kc + 8] = u1;
    }
    {
      const short* vp = vb + base + (size_t)(kv0 + vr) * Dh + vdb;
      bfx8 u0 = *(const bfx8*)vp;
      bfx8 u1 = *(const bfx8*)(vp + 8);
#pragma unroll
      for (int j = 0; j < 8; ++j) {
        Vt[(vdb + j) * LDK + vr] = u0[j];
        Vt[(vdb + 8 + j) * LDK + vr] = u1[j];
      }
    }
    __syncthreads();

    fx4 sa[4] = {};
#pragma unroll
    for (int nf = 0; nf < 4; ++nf) {
#pragma unroll
      for (int ks = 0; ks < 2; ++ks) {
        bfx8 kf = *(const bfx8*)&Ks[(nf * 16 + fr) * LDK + ks * 32 + fq * 8];
        sa[nf] = __builtin_amdgcn_mfma_f32_16x16x32_bf16(qf[ks], kf, sa[nf], 0, 0, 0);
      }
    }

#pragma unroll
    for (int i = 0; i < 4; ++i) {
      float mx = fmaxf(fmaxf(sa[0][i], sa[1][i]), fmaxf(sa[2][i], sa[3][i]));
      mx = fmaxf(mx, __shfl_xor(mx, 1));
      mx = fmaxf(mx, __shfl_xor(mx, 2));
      mx = fmaxf(mx, __shfl_xor(mx, 4));
      mx = fmaxf(mx, __shfl_xor(mx, 8));
      mx *= 0.125f;
      const float mn = fmaxf(mrow[i], mx);
      const float alpha = __expf(mrow[i] - mn);
      mrow[i] = mn;
      float rs = 0.f;
#pragma unroll
      for (int nf = 0; nf < 4; ++nf) {
        const float p = __expf(sa[nf][i] * 0.125f - mn);
        rs += p;
        Ps[wave][(fq * 4 + i) * LDK + nf * 16 + fr] = f2bf(p);
      }
      rs += __shfl_xor(rs, 1);
      rs += __shfl_xor(rs, 2);
      rs += __shfl_xor(rs, 4);
      rs += __shfl_xor(rs, 8);
      lrow[i] = lrow[i] * alpha + rs;
#pragma unroll
      for (int df = 0; df < 4; ++df) oacc[df][i] *= alpha;
    }
    __syncthreads();

    bfx8 pf[2];
    pf[0] = *(const bfx8*)&Ps[wave][fr * LDK + fq * 8];
    pf[1] = *(const bfx8*)&Ps[wave][fr * LDK + 32 + fq * 8];
#pragma unroll
    for (int df = 0; df < 4; ++df) {
#pragma unroll
      for (int ks = 0; ks < 2; ++ks) {
        bfx8 vf = *(const bfx8*)&Vt[(df * 16 + fr) * LDK + ks * 32 + fq * 8];
        oacc[df] = __builtin_amdgcn_mfma_f32_16x16x32_bf16(pf[ks], vf, oacc[df], 0, 0, 0);
      }
    }
    __syncthreads();
  }

  const int b = bh >> 4, h = bh & 15;
#pragma unroll
  for (int df = 0; df < 4; ++df) {
    const int d = df * 16 + fr;
#pragma unroll
    for (int i = 0; i < 4; ++i) {
      const int qrow = q0 + fq * 4 + i;
      const float o = oacc[df][i] / lrow[i];
      wv[((size_t)b * Sq + qrow) * Em + h * Dh + d] = f2bf(o);
    }
  }
}

extern "C" void kernel_launch(void* const* d_in, const int* in_sizes, int n_in,
                              void* d_out, int out_size, void* d_ws, size_t ws_size,
                              hipStream_t stream) {
  (void)in_sizes; (void)n_in; (void)out_size; (void)ws_size;
  const float* query = (const float*)d_in[0];
  const float* key   = (const float*)d_in[1];
  const float* value = (const float*)d_in[2];
  const float* Wq = (const float*)d_in[3];
  const float* bq = (const float*)d_in[4];
  const float* Wk = (const float*)d_in[5];
  const float* bk = (const float*)d_in[6];
  const float* Wv = (const float*)d_in[7];
  const float* bv = (const float*)d_in[8];
  const float* Wo = (const float*)d_in[9];
  const float* bo = (const float*)d_in[10];
  const float* pos = (const float*)d_in[11];

  // ws layout (bf16 elements):
  //   qx,kx,vx: converted inputs (3 x 4M)       [qx dead after gemm_qkv -> wv aliases it]
  //   Wqb,Wkb,Wvb,Wob: converted weights (4 x 1M)
  //   qb: projected Q [B,H,S,Dh] (4M)
  // kb,vb (projected K,V) live in d_out (16MB f32 = 8M bf16), written before
  // any read and fully overwritten by gemm_out_bf16 -> deterministic replay.
  short* qx = (short*)d_ws;
  short* kx = qx + NE;
  short* vx = kx + NE;
  short* Wqb = vx + NE;
  short* Wkb = Wqb + WE;
  short* Wvb = Wkb + WE;
  short* Wob = Wvb + WE;
  short* qb = Wob + WE;
  short* wv = qx;                 // alias: qx dead after gemm_qkv
  short* kb = (short*)d_out;
  short* vb = kb + NE;

  convert_kernel<<<dim3(2048, 7), 256, 0, stream>>>(
      query, key, value, Wq, Wk, Wv, Wo, qx, kx, vx, Wqb, Wkb, Wvb, Wob);
  gemm_qkv_bf16<<<dim3(Mrows / 128, Em / 128, 3), 256, 0, stream>>>(
      qx, kx, vx, Wqb, Wkb, Wvb, bq, bk, bv, pos, qb, kb, vb);
  attn_kernel<<<dim3(Bz * Hn, Sq / 64), 256, 0, stream>>>(qb, kb, vb, wv);
  gemm_out_bf16<<<dim3(Mrows / 128, Em / 128), 256, 0, stream>>>(
      wv, Wob, bo, (float*)d_out);
}